// Round 7
// baseline (409.069 us; speedup 1.0000x reference)
//
#include <hip/hip_runtime.h>

// emb lookup -> RNN tanh(xp_t + h @ W_hh^T) over S=128 -> 5-class head.
// B=4096, S=128, D=256, VOCAB=50000. Floats f32, x int32, out f32.
//
// R13 structural move: DELETE the table-projection phase. Evidence: emb_proj
// was stuck at ~97us for a 77MB job across 4 structures (R0/R1/R4/R5), and
// rnn is a latency/pipe-sum at ~2450cy/step with MFMA only 21% busy. So:
//  - Phase 0 is now a trivial f32->bf16 convert of emb (pure streaming,
//    no barriers/MFMA -> BW-bound ~15-25us).
//  - rnn gathers bf16 EMB rows (same 512B/row as the old P rows) and folds
//    the W_ih projection into the step loop: xp(t+1) = bias + e(t+1)@W_ih^T
//    computed as 16 extra MFMAs per wave-step — independent of the h-chain,
//    so it fills the latency the counters say we can't otherwise hide.
//    xp stays f32 (no bf16 round-trip -> closer to reference).
//  - A-frag gather: lane(l15,quad) reads 16B at tok[l15]*512 + quad*16 +
//    kt*64 — ONE addr calc + 8 imm-offset dwordx4 loads; 8-wave redundancy
//    (all waves read the same 16 rows) absorbed by L1 (8KB/step working set).
//  - W_ih frags VGPR-resident (+64); launch_bounds(512,2) caps at 256.
//  - h-chain, swizzled h LDS, lgkm-only barriers (R6: slight gain), and
//    classifier identical to the best-measured R6 rnn.

typedef __attribute__((ext_vector_type(8))) short bf16x8;   // 8 bf16 = 4 VGPRs
typedef __attribute__((ext_vector_type(4))) float f32x4;    // MFMA 16x16 accumulator

#define VOCAB 50000

__device__ __align__(256) unsigned short g_E[VOCAB * 256];  // 25.6 MB bf16 emb table

static __device__ __forceinline__ float bf2f(unsigned short u) {
    union { unsigned int i; float f; } v; v.i = ((unsigned int)u) << 16; return v.f;
}
static __device__ __forceinline__ unsigned short f2bf_rne(float f) {
    union { float f; unsigned int i; } v; v.f = f;
    unsigned int r = v.i + 0x7FFFu + ((v.i >> 16) & 1u);
    return (unsigned short)(r >> 16);
}
static __device__ __forceinline__ unsigned short f2bf_fast(float f) {   // round-half-up
    union { float f; unsigned int i; } v; v.f = f;
    return (unsigned short)((v.i + 0x8000u) >> 16);
}
static __device__ __forceinline__ bf16x8 cvt8(float4 a, float4 b) {
    bf16x8 r;
    r[0] = (short)f2bf_rne(a.x); r[1] = (short)f2bf_rne(a.y);
    r[2] = (short)f2bf_rne(a.z); r[3] = (short)f2bf_rne(a.w);
    r[4] = (short)f2bf_rne(b.x); r[5] = (short)f2bf_rne(b.y);
    r[6] = (short)f2bf_rne(b.z); r[7] = (short)f2bf_rne(b.w);
    return r;
}
static __device__ __forceinline__ bf16x8 load8_bf(const float* __restrict__ p) {
    return cvt8(((const float4*)p)[0], ((const float4*)p)[1]);
}
// tanh(x) = 1 - 2/(e^{2x}+1); med3 clamp keeps exp finite
static __device__ __forceinline__ float fast_tanh(float x) {
    x = __builtin_amdgcn_fmed3f(x, -8.f, 8.f);
    float e = __expf(2.f * x);
    return __builtin_fmaf(-2.f, __builtin_amdgcn_rcpf(e + 1.f), 1.f);
}
// Workgroup barrier that does NOT drain vmcnt: only LDS ops must be visible.
// All cross-wave hazards in rnn are LDS<->LDS (h, tok_t, wcls); in-flight
// global gathers keep counted vmcnt waits at their consumption sites.
static __device__ __forceinline__ void barrier_lds_only() {
    asm volatile("s_waitcnt lgkmcnt(0)\n\ts_barrier" ::: "memory");
}

// ---------------- Phase 0: g_E = bf16(emb), pure streaming ----------------
__global__ __launch_bounds__(256)
void emb_cvt_kernel(const float* __restrict__ emb)
{
    const int nunits = VOCAB * 256 / 8;   // 1,600,000 units of 8 floats
    int gid = blockIdx.x * 256 + threadIdx.x;
    int stride = gridDim.x * 256;
    for (int u = gid; u < nunits; u += stride) {
        const float4* s = (const float4*)(emb + (size_t)u * 8);
        float4 a = s[0], b = s[1];
        *(bf16x8*)(g_E + (size_t)u * 8) = cvt8(a, b);
    }
}

// ---------------- Phase 1: fused projection + recurrence + classifier ----------------
// 256 blocks x 16 rows x 512 thr (8 waves x 32 cols). h LDS layout (per 8KB
// buffer): element (row m, col c) at byte m*512 + (((c>>3)^m)<<4) + (c&7)*2.
__global__ __launch_bounds__(512, 2)
void rnn_kernel(const int* __restrict__ x,
                const float* __restrict__ W_ih,
                const float* __restrict__ W_hh,
                const float* __restrict__ b_ih,
                const float* __restrict__ b_hh,
                const float* __restrict__ W_cls,
                const float* __restrict__ b_cls,
                float* __restrict__ out)
{
    __shared__ __align__(16) unsigned short h_lds[2][16 * 256];  // 2 x 8 KB
    __shared__ __align__(16) int tok_t[128 * 16];                // [t][row]
    __shared__ __align__(16) float wcls_lds[5 * 256];
    __shared__ float bcls_lds[5];

    const int tid  = threadIdx.x;
    const int lane = tid & 63;
    const int wid  = tid >> 6;          // 8 waves
    const int b0   = blockIdx.x * 16;
    const int n0   = wid * 32;          // wave's 32-col slice
    const int l15  = lane & 15;
    const int quad = lane >> 4;

    // W_hh and W_ih -> bf16 B-fragments, VGPR-resident (64 + 64 VGPR)
    bf16x8 wfh[2][8], wfi[2][8];
    float  bias[2];
    #pragma unroll
    for (int nt = 0; nt < 2; ++nt) {
        int n = n0 + nt * 16 + l15;
        bias[nt] = b_ih[n] + b_hh[n];
        #pragma unroll
        for (int kt = 0; kt < 8; ++kt) {
            wfh[nt][kt] = load8_bf(W_hh + n * 256 + quad * 8 + kt * 32);
            wfi[nt][kt] = load8_bf(W_ih + n * 256 + quad * 8 + kt * 32);
        }
    }

    // stage tokens transposed: tok_t[t*16 + row]
    {
        int row = tid & 15, tq = tid >> 4;   // tq 0..31
        int4 v = *(const int4*)(x + (size_t)(b0 + row) * 128 + tq * 4);
        tok_t[(tq * 4 + 0) * 16 + row] = v.x;
        tok_t[(tq * 4 + 1) * 16 + row] = v.y;
        tok_t[(tq * 4 + 2) * 16 + row] = v.z;
        tok_t[(tq * 4 + 3) * 16 + row] = v.w;
    }
    if (tid < 320) ((float4*)wcls_lds)[tid] = ((const float4*)W_cls)[tid];
    if (tid < 5)   bcls_lds[tid] = b_cls[tid];
    #pragma unroll
    for (int i = 0; i < 4; ++i) ((unsigned int*)h_lds[0])[tid + i * 512] = 0;

    // precomputed LDS byte offsets (loop-invariant; buf1 = +8192 imm)
    int aoff[8];
    #pragma unroll
    for (int kt = 0; kt < 8; ++kt)
        aoff[kt] = l15 * 512 + (((quad + 4 * kt) ^ l15) << 4);
    int woff[8];   // [nt*4 + r]
    #pragma unroll
    for (int nt = 0; nt < 2; ++nt)
        #pragma unroll
        for (int r = 0; r < 4; ++r) {
            int row = quad * 4 + r;
            int g   = (n0 >> 3) + nt * 2 + (l15 >> 3);
            woff[nt * 4 + r] = row * 512 + ((g ^ row) << 4) + (l15 & 7) * 2;
        }

    const char* const gE = (const char*)g_E;

    // prologue: gather e(0) via x directly (tok_t not yet visible), xp(0) -> xe
    f32x4 xe0, xe1, xo0, xo1;
    {
        int tk = x[(size_t)(b0 + l15) * 128];
        unsigned toff = (unsigned)tk * 512 + quad * 16;
        bf16x8 e0[8];
        #pragma unroll
        for (int kt = 0; kt < 8; ++kt)
            e0[kt] = *(const bf16x8*)(gE + toff + kt * 64);
        xe0 = (f32x4){bias[0], bias[0], bias[0], bias[0]};
        xe1 = (f32x4){bias[1], bias[1], bias[1], bias[1]};
        #pragma unroll
        for (int kt = 0; kt < 8; ++kt) {
            xe0 = __builtin_amdgcn_mfma_f32_16x16x32_bf16(e0[kt], wfi[0][kt], xe0, 0, 0, 0);
            xe1 = __builtin_amdgcn_mfma_f32_16x16x32_bf16(e0[kt], wfi[1][kt], xe1, 0, 0, 0);
        }
    }
    __syncthreads();   // tok_t / wcls / h zero visible

    char* const h0 = (char*)&h_lds[0][0];

    // step t: consume xp(t) in (c0,c1) as h-MFMA C-init; gather e(t+1) and
    // produce xp(t+1) into (p0,p1). xp-MFMAs are independent of the h-chain.
    auto step = [&](const char* hA, char* hW, f32x4& c0, f32x4& c1,
                    f32x4& p0, f32x4& p1, int t) {
        bf16x8 eF[8];
        const bool gg = (t + 1 < 128);
        if (gg) {
            int tk = tok_t[(t + 1) * 16 + l15];
            unsigned toff = (unsigned)tk * 512 + quad * 16;
            #pragma unroll
            for (int kt = 0; kt < 8; ++kt)
                eF[kt] = *(const bf16x8*)(gE + toff + kt * 64);
        }
        #pragma unroll
        for (int kt = 0; kt < 8; ++kt) {
            bf16x8 a = *(const bf16x8*)(hA + aoff[kt]);
            c0 = __builtin_amdgcn_mfma_f32_16x16x32_bf16(a, wfh[0][kt], c0, 0, 0, 0);
            c1 = __builtin_amdgcn_mfma_f32_16x16x32_bf16(a, wfh[1][kt], c1, 0, 0, 0);
        }
        #pragma unroll
        for (int r = 0; r < 4; ++r) {
            *(unsigned short*)(hW + woff[r])     = f2bf_fast(fast_tanh(c0[r]));
            *(unsigned short*)(hW + woff[4 + r]) = f2bf_fast(fast_tanh(c1[r]));
        }
        if (gg) {
            p0 = (f32x4){bias[0], bias[0], bias[0], bias[0]};
            p1 = (f32x4){bias[1], bias[1], bias[1], bias[1]};
            #pragma unroll
            for (int kt = 0; kt < 8; ++kt) {
                p0 = __builtin_amdgcn_mfma_f32_16x16x32_bf16(eF[kt], wfi[0][kt], p0, 0, 0, 0);
                p1 = __builtin_amdgcn_mfma_f32_16x16x32_bf16(eF[kt], wfi[1][kt], p1, 0, 0, 0);
            }
        }
        barrier_lds_only();
    };

    #pragma unroll 1
    for (int t2 = 0; t2 < 64; ++t2) {
        step(h0,        h0 + 8192, xe0, xe1, xo0, xo1, 2 * t2);      // read buf0, write buf1
        step(h0 + 8192, h0,        xo0, xo1, xe0, xe1, 2 * t2 + 1);  // read buf1, write buf0
    }

    // final h in buf0 (step 127 wrote buf0). Classifier: 4 threads per (row,c).
    if (tid < 320) {
        int q = tid & 3, p = tid >> 2;
        int row = p / 5, c = p - row * 5;
        float acc = 0.f;
        #pragma unroll
        for (int kk = 0; kk < 64; ++kk) {
            int k = q * 64 + kk;
            int off = row * 512 + ((((k >> 3) ^ row)) << 4) + (k & 7) * 2;
            acc += bf2f(*(const unsigned short*)(h0 + off)) * wcls_lds[c * 256 + k];
        }
        acc += __shfl_xor(acc, 1);
        acc += __shfl_xor(acc, 2);
        if (q == 0) out[(size_t)(b0 + row) * 5 + c] = acc + bcls_lds[c];
    }
}

extern "C" void kernel_launch(void* const* d_in, const int* in_sizes, int n_in,
                              void* d_out, int out_size, void* d_ws, size_t ws_size,
                              hipStream_t stream)
{
    const int*   x     = (const int*)d_in[0];
    const float* emb   = (const float*)d_in[1];
    const float* W_ih  = (const float*)d_in[2];
    const float* W_hh  = (const float*)d_in[3];
    const float* b_ih  = (const float*)d_in[4];
    const float* b_hh  = (const float*)d_in[5];
    const float* W_cls = (const float*)d_in[6];
    const float* b_cls = (const float*)d_in[7];
    float*       out   = (float*)d_out;
    (void)d_ws; (void)ws_size;

    emb_cvt_kernel<<<2048, 256, 0, stream>>>(emb);
    rnn_kernel<<<256, 512, 0, stream>>>(x, W_ih, W_hh, b_ih, b_hh, W_cls, b_cls, out);
}

// Round 8
// 405.346 us; speedup vs baseline: 1.0092x; 1.0092x over previous
//
#include <hip/hip_runtime.h>

// emb lookup -> RNN tanh(xp_t + h @ W_hh^T) over S=128 -> 5-class head.
// B=4096, S=128, D=256, VOCAB=50000. Floats f32, x int32, out f32.
//
// R14: fused design (R13) with the spill fixed and gather latency covered.
// R13 evidence: VGPR capped at 128 by launch_bounds(512,2) (empirical cap =
// 512-reg/SIMD pool / 4 waves) -> ~35MB scratch writes, MfmaUtil 17%, 335us.
// Fixes:
//  - __launch_bounds__(512,1): ~240 VGPR allocation; 8 waves/block still
//    resident (2 waves/SIMD x 240 = 480 <= 512 pool), occupancy unchanged
//    vs the 130us baseline rnn.
//  - e-gather deepened to 2-step distance (eA/eB ping-pong): gather e(t+2)
//    at step t, compute xp(t+1) = bias + e(t+1)@W_ih^T (gathered a full step
//    ago, ~2000cy in flight), consume xp(t) as h-MFMA C-init. xp stays f32.
//  - Phase 0 is the trivial f32->bf16 stream (emb -> g_E).
// Unique gather bytes/block-step identical to the g_P design (16 x 512B);
// 8-wave A-frag redundancy absorbed by L1 (8KB working set).

typedef __attribute__((ext_vector_type(8))) short bf16x8;   // 8 bf16 = 4 VGPRs
typedef __attribute__((ext_vector_type(4))) float f32x4;    // MFMA 16x16 accumulator

#define VOCAB 50000

__device__ __align__(256) unsigned short g_E[VOCAB * 256];  // 25.6 MB bf16 emb table

static __device__ __forceinline__ float bf2f(unsigned short u) {
    union { unsigned int i; float f; } v; v.i = ((unsigned int)u) << 16; return v.f;
}
static __device__ __forceinline__ unsigned short f2bf_rne(float f) {
    union { float f; unsigned int i; } v; v.f = f;
    unsigned int r = v.i + 0x7FFFu + ((v.i >> 16) & 1u);
    return (unsigned short)(r >> 16);
}
static __device__ __forceinline__ unsigned short f2bf_fast(float f) {   // round-half-up
    union { float f; unsigned int i; } v; v.f = f;
    return (unsigned short)((v.i + 0x8000u) >> 16);
}
static __device__ __forceinline__ bf16x8 cvt8(float4 a, float4 b) {
    bf16x8 r;
    r[0] = (short)f2bf_rne(a.x); r[1] = (short)f2bf_rne(a.y);
    r[2] = (short)f2bf_rne(a.z); r[3] = (short)f2bf_rne(a.w);
    r[4] = (short)f2bf_rne(b.x); r[5] = (short)f2bf_rne(b.y);
    r[6] = (short)f2bf_rne(b.z); r[7] = (short)f2bf_rne(b.w);
    return r;
}
static __device__ __forceinline__ bf16x8 load8_bf(const float* __restrict__ p) {
    return cvt8(((const float4*)p)[0], ((const float4*)p)[1]);
}
// tanh(x) = 1 - 2/(e^{2x}+1); med3 clamp keeps exp finite
static __device__ __forceinline__ float fast_tanh(float x) {
    x = __builtin_amdgcn_fmed3f(x, -8.f, 8.f);
    float e = __expf(2.f * x);
    return __builtin_fmaf(-2.f, __builtin_amdgcn_rcpf(e + 1.f), 1.f);
}
// Workgroup barrier that does NOT drain vmcnt: only LDS ops must be visible.
// All cross-wave hazards in rnn are LDS<->LDS (h, tok_t, wcls); in-flight
// global gathers keep counted vmcnt waits at their consumption sites.
static __device__ __forceinline__ void barrier_lds_only() {
    asm volatile("s_waitcnt lgkmcnt(0)\n\ts_barrier" ::: "memory");
}

// ---------------- Phase 0: g_E = bf16(emb), pure streaming ----------------
__global__ __launch_bounds__(256)
void emb_cvt_kernel(const float* __restrict__ emb)
{
    const int nunits = VOCAB * 256 / 8;   // 1,600,000 units of 8 floats
    int gid = blockIdx.x * 256 + threadIdx.x;
    int stride = gridDim.x * 256;
    for (int u = gid; u < nunits; u += stride) {
        const float4* s = (const float4*)(emb + (size_t)u * 8);
        float4 a = s[0], b = s[1];
        *(bf16x8*)(g_E + (size_t)u * 8) = cvt8(a, b);
    }
}

// ---------------- Phase 1: fused projection + recurrence + classifier ----------------
// 256 blocks x 16 rows x 512 thr (8 waves x 32 cols). h LDS layout (per 8KB
// buffer): element (row m, col c) at byte m*512 + (((c>>3)^m)<<4) + (c&7)*2.
__global__ __launch_bounds__(512, 1)
void rnn_kernel(const int* __restrict__ x,
                const float* __restrict__ W_ih,
                const float* __restrict__ W_hh,
                const float* __restrict__ b_ih,
                const float* __restrict__ b_hh,
                const float* __restrict__ W_cls,
                const float* __restrict__ b_cls,
                float* __restrict__ out)
{
    __shared__ __align__(16) unsigned short h_lds[2][16 * 256];  // 2 x 8 KB
    __shared__ __align__(16) int tok_t[128 * 16];                // [t][row]
    __shared__ __align__(16) float wcls_lds[5 * 256];
    __shared__ float bcls_lds[5];

    const int tid  = threadIdx.x;
    const int lane = tid & 63;
    const int wid  = tid >> 6;          // 8 waves
    const int b0   = blockIdx.x * 16;
    const int n0   = wid * 32;          // wave's 32-col slice
    const int l15  = lane & 15;
    const int quad = lane >> 4;

    // W_hh and W_ih -> bf16 B-fragments, VGPR-resident (64 + 64 VGPR)
    bf16x8 wfh[2][8], wfi[2][8];
    float  bias[2];
    #pragma unroll
    for (int nt = 0; nt < 2; ++nt) {
        int n = n0 + nt * 16 + l15;
        bias[nt] = b_ih[n] + b_hh[n];
        #pragma unroll
        for (int kt = 0; kt < 8; ++kt) {
            wfh[nt][kt] = load8_bf(W_hh + n * 256 + quad * 8 + kt * 32);
            wfi[nt][kt] = load8_bf(W_ih + n * 256 + quad * 8 + kt * 32);
        }
    }

    // stage tokens transposed: tok_t[t*16 + row]
    {
        int row = tid & 15, tq = tid >> 4;   // tq 0..31
        int4 v = *(const int4*)(x + (size_t)(b0 + row) * 128 + tq * 4);
        tok_t[(tq * 4 + 0) * 16 + row] = v.x;
        tok_t[(tq * 4 + 1) * 16 + row] = v.y;
        tok_t[(tq * 4 + 2) * 16 + row] = v.z;
        tok_t[(tq * 4 + 3) * 16 + row] = v.w;
    }
    if (tid < 320) ((float4*)wcls_lds)[tid] = ((const float4*)W_cls)[tid];
    if (tid < 5)   bcls_lds[tid] = b_cls[tid];
    #pragma unroll
    for (int i = 0; i < 4; ++i) ((unsigned int*)h_lds[0])[tid + i * 512] = 0;

    // precomputed LDS byte offsets (loop-invariant; buf1 = +8192 imm)
    int aoff[8];
    #pragma unroll
    for (int kt = 0; kt < 8; ++kt)
        aoff[kt] = l15 * 512 + (((quad + 4 * kt) ^ l15) << 4);
    int woff[8];   // [nt*4 + r]
    #pragma unroll
    for (int nt = 0; nt < 2; ++nt)
        #pragma unroll
        for (int r = 0; r < 4; ++r) {
            int row = quad * 4 + r;
            int g   = (n0 >> 3) + nt * 2 + (l15 >> 3);
            woff[nt * 4 + r] = row * 512 + ((g ^ row) << 4) + (l15 & 7) * 2;
        }

    const char* const gE = (const char*)g_E;

    // prologue: gather e(0) -> eA and e(1) -> eB directly via x (tok_t not yet
    // visible); compute xp(0) -> (xe0,xe1). eA is then dead (reused as eNext).
    f32x4 xe0, xe1, xo0, xo1;
    bf16x8 eA[8], eB[8];
    {
        const int* xr = x + (size_t)(b0 + l15) * 128;
        unsigned t0off = (unsigned)xr[0] * 512 + quad * 16;
        unsigned t1off = (unsigned)xr[1] * 512 + quad * 16;
        #pragma unroll
        for (int kt = 0; kt < 8; ++kt) {
            eA[kt] = *(const bf16x8*)(gE + t0off + kt * 64);
            eB[kt] = *(const bf16x8*)(gE + t1off + kt * 64);
        }
        xe0 = (f32x4){bias[0], bias[0], bias[0], bias[0]};
        xe1 = (f32x4){bias[1], bias[1], bias[1], bias[1]};
        #pragma unroll
        for (int kt = 0; kt < 8; ++kt) {
            xe0 = __builtin_amdgcn_mfma_f32_16x16x32_bf16(eA[kt], wfi[0][kt], xe0, 0, 0, 0);
            xe1 = __builtin_amdgcn_mfma_f32_16x16x32_bf16(eA[kt], wfi[1][kt], xe1, 0, 0, 0);
        }
    }
    __syncthreads();   // tok_t / wcls / h zero visible

    char* const h0 = (char*)&h_lds[0][0];

    // step t: consume xp(t) in (c0,c1) as h-MFMA C-init; gather e(t+2) -> eNext;
    // compute xp(t+1) from eCur (gathered at step t-1, a full step in flight).
    auto step = [&](const char* hA, char* hW, f32x4& c0, f32x4& c1,
                    f32x4& p0, f32x4& p1, bf16x8* eCur, bf16x8* eNext, int t) {
        if (t + 2 < 128) {
            int tk = tok_t[(t + 2) * 16 + l15];
            unsigned toff = (unsigned)tk * 512 + quad * 16;
            #pragma unroll
            for (int kt = 0; kt < 8; ++kt)
                eNext[kt] = *(const bf16x8*)(gE + toff + kt * 64);
        }
        #pragma unroll
        for (int kt = 0; kt < 8; ++kt) {
            bf16x8 a = *(const bf16x8*)(hA + aoff[kt]);
            c0 = __builtin_amdgcn_mfma_f32_16x16x32_bf16(a, wfh[0][kt], c0, 0, 0, 0);
            c1 = __builtin_amdgcn_mfma_f32_16x16x32_bf16(a, wfh[1][kt], c1, 0, 0, 0);
        }
        if (t + 1 < 128) {
            p0 = (f32x4){bias[0], bias[0], bias[0], bias[0]};
            p1 = (f32x4){bias[1], bias[1], bias[1], bias[1]};
            #pragma unroll
            for (int kt = 0; kt < 8; ++kt) {
                p0 = __builtin_amdgcn_mfma_f32_16x16x32_bf16(eCur[kt], wfi[0][kt], p0, 0, 0, 0);
                p1 = __builtin_amdgcn_mfma_f32_16x16x32_bf16(eCur[kt], wfi[1][kt], p1, 0, 0, 0);
            }
        }
        #pragma unroll
        for (int r = 0; r < 4; ++r) {
            *(unsigned short*)(hW + woff[r])     = f2bf_fast(fast_tanh(c0[r]));
            *(unsigned short*)(hW + woff[4 + r]) = f2bf_fast(fast_tanh(c1[r]));
        }
        barrier_lds_only();
    };

    #pragma unroll 1
    for (int t2 = 0; t2 < 64; ++t2) {
        // t even: eCur = eB (= e(t+1)), eNext -> eA
        step(h0,        h0 + 8192, xe0, xe1, xo0, xo1, eB, eA, 2 * t2);
        // t odd:  eCur = eA (= e(t+1)), eNext -> eB
        step(h0 + 8192, h0,        xo0, xo1, xe0, xe1, eA, eB, 2 * t2 + 1);
    }

    // final h in buf0 (step 127 wrote buf0). Classifier: 4 threads per (row,c).
    if (tid < 320) {
        int q = tid & 3, p = tid >> 2;
        int row = p / 5, c = p - row * 5;
        float acc = 0.f;
        #pragma unroll
        for (int kk = 0; kk < 64; ++kk) {
            int k = q * 64 + kk;
            int off = row * 512 + ((((k >> 3) ^ row)) << 4) + (k & 7) * 2;
            acc += bf2f(*(const unsigned short*)(h0 + off)) * wcls_lds[c * 256 + k];
        }
        acc += __shfl_xor(acc, 1);
        acc += __shfl_xor(acc, 2);
        if (q == 0) out[(size_t)(b0 + row) * 5 + c] = acc + bcls_lds[c];
    }
}

extern "C" void kernel_launch(void* const* d_in, const int* in_sizes, int n_in,
                              void* d_out, int out_size, void* d_ws, size_t ws_size,
                              hipStream_t stream)
{
    const int*   x     = (const int*)d_in[0];
    const float* emb   = (const float*)d_in[1];
    const float* W_ih  = (const float*)d_in[2];
    const float* W_hh  = (const float*)d_in[3];
    const float* b_ih  = (const float*)d_in[4];
    const float* b_hh  = (const float*)d_in[5];
    const float* W_cls = (const float*)d_in[6];
    const float* b_cls = (const float*)d_in[7];
    float*       out   = (float*)d_out;
    (void)d_ws; (void)ws_size;

    emb_cvt_kernel<<<2048, 256, 0, stream>>>(emb);
    rnn_kernel<<<256, 512, 0, stream>>>(x, W_ih, W_hh, b_ih, b_hh, W_cls, b_cls, out);
}

// Round 9
// 294.112 us; speedup vs baseline: 1.3909x; 1.3782x over previous
//
#include <hip/hip_runtime.h>
#include <hip/hip_cooperative_groups.h>

namespace cg = cooperative_groups;

// emb lookup -> RNN tanh(xp_t + h @ W_hh^T) over S=128 -> 5-class head.
// B=4096, S=128, D=256, VOCAB=50000. Floats f32, x int32, out f32.
//
// R15: SINGLE cooperative kernel: [phase A: P = bf16(emb@W_ih^T + bias)]
// -> grid.sync() -> [phase C: R6 rnn body, best measured 130.5us].
// Session model: every kernel runs at ~0.9-1.1 TB/s of L2-miss traffic;
// durations = bytes/BW. Gains vs two-kernel 226us: no inter-dispatch gap;
// phase A gets 8 waves/block (2/SIMD vs R0-emb's 1/SIMD -> latency hiding);
// staging overlaps. R7/R8's fusion spills were rule-#20 (runtime-pointer
// arrays), NOT launch-bounds: here all arrays are static-indexed; live VGPR
// ~110 (A) / ~100 (C) fits the empirical 128 cap.
// Phase A = R4's proven single-lgkm-barrier double-buffer tile loop at 512
// thr: 16-row tiles, 13 tiles/block max, 2-tile reg prefetch, direct g_P
// stores. Phase C = R6 verbatim (depth-4 gather pipeline, lgkm barriers).
// Arithmetic bit-identical to R6 (same cvt/MFMA/rounding order).

typedef __attribute__((ext_vector_type(8))) short bf16x8;   // 8 bf16 = 4 VGPRs
typedef __attribute__((ext_vector_type(4))) float f32x4;    // MFMA 16x16 accumulator

#define VOCAB 50000
#define LDS_STRIDE 264   // phase A staging stride (ushorts)

__device__ __align__(256) unsigned short g_P[VOCAB * 256];  // 25.6 MB projected table

static __device__ __forceinline__ float bf2f(unsigned short u) {
    union { unsigned int i; float f; } v; v.i = ((unsigned int)u) << 16; return v.f;
}
static __device__ __forceinline__ float bfbits2f(unsigned int zext_u16) {
    union { unsigned int i; float f; } v; v.i = zext_u16 << 16; return v.f;
}
static __device__ __forceinline__ unsigned short f2bf_rne(float f) {
    union { float f; unsigned int i; } v; v.f = f;
    unsigned int r = v.i + 0x7FFFu + ((v.i >> 16) & 1u);
    return (unsigned short)(r >> 16);
}
static __device__ __forceinline__ unsigned short f2bf_fast(float f) {   // round-half-up
    union { float f; unsigned int i; } v; v.f = f;
    return (unsigned short)((v.i + 0x8000u) >> 16);
}
static __device__ __forceinline__ bf16x8 cvt8(float4 a, float4 b) {
    bf16x8 r;
    r[0] = (short)f2bf_rne(a.x); r[1] = (short)f2bf_rne(a.y);
    r[2] = (short)f2bf_rne(a.z); r[3] = (short)f2bf_rne(a.w);
    r[4] = (short)f2bf_rne(b.x); r[5] = (short)f2bf_rne(b.y);
    r[6] = (short)f2bf_rne(b.z); r[7] = (short)f2bf_rne(b.w);
    return r;
}
static __device__ __forceinline__ bf16x8 load8_bf(const float* __restrict__ p) {
    return cvt8(((const float4*)p)[0], ((const float4*)p)[1]);
}
// tanh(x) = 1 - 2/(e^{2x}+1); med3 clamp keeps exp finite
static __device__ __forceinline__ float fast_tanh(float x) {
    x = __builtin_amdgcn_fmed3f(x, -8.f, 8.f);
    float e = __expf(2.f * x);
    return __builtin_fmaf(-2.f, __builtin_amdgcn_rcpf(e + 1.f), 1.f);
}
// Workgroup barrier that does NOT drain vmcnt: only LDS ops must be visible.
static __device__ __forceinline__ void barrier_lds_only() {
    asm volatile("s_waitcnt lgkmcnt(0)\n\ts_barrier" ::: "memory");
}

// ---------------- fused: projection -> grid sync -> recurrence ----------------
__global__ __launch_bounds__(512, 2)
void rnn_fused_kernel(const int* __restrict__ x,
                      const float* __restrict__ emb,
                      const float* __restrict__ W_ih,
                      const float* __restrict__ W_hh,
                      const float* __restrict__ b_ih,
                      const float* __restrict__ b_hh,
                      const float* __restrict__ W_cls,
                      const float* __restrict__ b_cls,
                      float* __restrict__ out)
{
    __shared__ __align__(16) unsigned short tin[2][16 * LDS_STRIDE];  // 16.9 KB (phase A)
    __shared__ __align__(16) unsigned short h_lds[2][16 * 256];       // 16 KB
    __shared__ __align__(16) int tok_t[128 * 16];                     // 8 KB
    __shared__ __align__(16) float wcls_lds[5 * 256];                 // 5 KB
    __shared__ float bcls_lds[5];

    const int tid  = threadIdx.x;
    const int lane = tid & 63;
    const int wid  = tid >> 6;          // 8 waves
    const int b    = blockIdx.x;        // 256 blocks, 1 per CU
    const int b0   = b * 16;
    const int n0   = wid * 32;          // wave's 32-col slice (both phases)
    const int l15  = lane & 15;
    const int quad = lane >> 4;

    // ---- staging that overlaps phase A (all LDS; visible after barriers) ----
    {   // tokens transposed: tok_t[t*16 + row]
        int row = tid & 15, tq = tid >> 4;   // tq 0..31
        int4 v = *(const int4*)(x + (size_t)(b0 + row) * 128 + tq * 4);
        tok_t[(tq * 4 + 0) * 16 + row] = v.x;
        tok_t[(tq * 4 + 1) * 16 + row] = v.y;
        tok_t[(tq * 4 + 2) * 16 + row] = v.z;
        tok_t[(tq * 4 + 3) * 16 + row] = v.w;
    }
    if (tid < 320) ((float4*)wcls_lds)[tid] = ((const float4*)W_cls)[tid];
    if (tid < 5)   bcls_lds[tid] = b_cls[tid];
    #pragma unroll
    for (int i = 0; i < 4; ++i) ((unsigned int*)h_lds[0])[tid + i * 512] = 0;

    // ================= Phase A: P = bf16(emb @ W_ih^T + (b_ih + b_hh)) =================
    // 8 waves x 2 col-tiles. Tiles b, b+256, ... (13 max). Single lgkm barrier
    // per tile (R4 hazard proof: iter i writes tin[i&1] pre-barrier, reads it
    // post-barrier; the buffer overwritten next iter was last read pre-barrier(i)).
    {
        bf16x8 wfA[2][8];
        float  biasA[2];
        #pragma unroll
        for (int nt = 0; nt < 2; ++nt) {
            int n = n0 + nt * 16 + l15;
            biasA[nt] = b_ih[n] + b_hh[n];
            #pragma unroll
            for (int kt = 0; kt < 8; ++kt)
                wfA[nt][kt] = load8_bf(W_ih + n * 256 + quad * 8 + kt * 32);
        }

        const int srow = tid >> 5, sseg = tid & 31;   // staging map: 16 rows x 32 segs x 8 floats
        float4 p0a, p0b, p1a, p1b;                     // 2-tile register prefetch (static names)
        {
            const float4* s0 = (const float4*)(emb + ((size_t)b * 16 + srow) * 256 + sseg * 8);
            p0a = s0[0]; p0b = s0[1];
            int t1 = b + 256;
            if (t1 < 3125) {
                const float4* s1 = (const float4*)(emb + ((size_t)t1 * 16 + srow) * 256 + sseg * 8);
                p1a = s1[0]; p1b = s1[1];
            }
        }

        #define PROJ_STEP(I, PA, PB, TBUF)                                                 \
        {                                                                                  \
            int tile = b + (I) * 256;                                                      \
            if (tile < 3125) {                                                             \
                *(bf16x8*)(&TBUF[srow * LDS_STRIDE + sseg * 8]) = cvt8(PA, PB);            \
                int tf = tile + 512;                                                       \
                if (tf < 3125) {                                                           \
                    const float4* s = (const float4*)(emb + ((size_t)tf * 16 + srow) * 256 + sseg * 8); \
                    PA = s[0]; PB = s[1];                                                  \
                }                                                                          \
                barrier_lds_only();                                                        \
                f32x4 acc0 = (f32x4){0.f, 0.f, 0.f, 0.f};                                  \
                f32x4 acc1 = (f32x4){0.f, 0.f, 0.f, 0.f};                                  \
                _Pragma("unroll")                                                          \
                for (int kt = 0; kt < 8; ++kt) {                                           \
                    bf16x8 a = *(bf16x8*)(&TBUF[l15 * LDS_STRIDE + quad * 8 + kt * 32]);   \
                    acc0 = __builtin_amdgcn_mfma_f32_16x16x32_bf16(a, wfA[0][kt], acc0, 0, 0, 0); \
                    acc1 = __builtin_amdgcn_mfma_f32_16x16x32_bf16(a, wfA[1][kt], acc1, 0, 0, 0); \
                }                                                                          \
                unsigned short* prow = g_P + ((size_t)tile * 16 + quad * 4) * 256 + n0;    \
                _Pragma("unroll")                                                          \
                for (int r = 0; r < 4; ++r) {                                              \
                    prow[r * 256 + l15]      = f2bf_rne(acc0[r] + biasA[0]);               \
                    prow[r * 256 + 16 + l15] = f2bf_rne(acc1[r] + biasA[1]);               \
                }                                                                          \
            }                                                                              \
        }

        #pragma unroll 1
        for (int i2 = 0; i2 < 7; ++i2) {
            PROJ_STEP(2 * i2,     p0a, p0b, tin[0]);
            PROJ_STEP(2 * i2 + 1, p1a, p1b, tin[1]);
        }
        #undef PROJ_STEP
    }

    // ================= grid-wide sync: g_P complete & visible =================
    cg::this_grid().sync();

    // ================= Phase C: recurrence + classifier (R6 verbatim) =================
    // h LDS layout (per 8KB buffer): element (row m, col c) at byte
    //   m*512 + (((c>>3) ^ m) << 4) + (c&7)*2   (granule-XOR swizzle)
    bf16x8 wfh[2][8];
    #pragma unroll
    for (int nt = 0; nt < 2; ++nt) {
        int n = n0 + nt * 16 + l15;
        #pragma unroll
        for (int kt = 0; kt < 8; ++kt)
            wfh[nt][kt] = load8_bf(W_hh + n * 256 + quad * 8 + kt * 32);
    }

    int aoff[8];
    #pragma unroll
    for (int kt = 0; kt < 8; ++kt)
        aoff[kt] = l15 * 512 + (((quad + 4 * kt) ^ l15) << 4);
    int woff[8];   // [nt*4 + r]
    #pragma unroll
    for (int nt = 0; nt < 2; ++nt)
        #pragma unroll
        for (int r = 0; r < 4; ++r) {
            int row = quad * 4 + r;
            int g   = (n0 >> 3) + nt * 2 + (l15 >> 3);
            woff[nt * 4 + r] = row * 512 + ((g ^ row) << 4) + (l15 & 7) * 2;
        }

    const unsigned int colByte = (unsigned int)(n0 + l15) * 2;   // within a g_P row

    // prologue: gather xp(t=0..3) -> gA..gD (4-step-deep pipeline)
    unsigned int gA[8], gB[8], gC[8], gD[8];
    #pragma unroll
    for (int r = 0; r < 4; ++r) {
        const int* xr = x + (size_t)(b0 + quad * 4 + r) * 128;
        const unsigned short* p0 = g_P + (size_t)xr[0] * 256 + n0 + l15;
        const unsigned short* p1 = g_P + (size_t)xr[1] * 256 + n0 + l15;
        const unsigned short* p2 = g_P + (size_t)xr[2] * 256 + n0 + l15;
        const unsigned short* p3 = g_P + (size_t)xr[3] * 256 + n0 + l15;
        gA[r] = p0[0]; gA[4 + r] = p0[16];
        gB[r] = p1[0]; gB[4 + r] = p1[16];
        gC[r] = p2[0]; gC[4 + r] = p2[16];
        gD[r] = p3[0]; gD[4 + r] = p3[16];
    }
    barrier_lds_only();

    char* const h0 = (char*)&h_lds[0][0];

    auto step = [&](const char* hA, char* hW, unsigned int* g, int t) {
        f32x4 acc0 = { bfbits2f(g[0]), bfbits2f(g[1]), bfbits2f(g[2]), bfbits2f(g[3]) };
        f32x4 acc1 = { bfbits2f(g[4]), bfbits2f(g[5]), bfbits2f(g[6]), bfbits2f(g[7]) };
        if (t + 4 < 128) {
            int4 tk = *(const int4*)&tok_t[(t + 4) * 16 + quad * 4];
            const unsigned short* r0 = (const unsigned short*)((const char*)g_P + ((unsigned int)tk.x * 512 + colByte));
            const unsigned short* r1 = (const unsigned short*)((const char*)g_P + ((unsigned int)tk.y * 512 + colByte));
            const unsigned short* r2 = (const unsigned short*)((const char*)g_P + ((unsigned int)tk.z * 512 + colByte));
            const unsigned short* r3 = (const unsigned short*)((const char*)g_P + ((unsigned int)tk.w * 512 + colByte));
            g[0] = r0[0]; g[4] = r0[16];
            g[1] = r1[0]; g[5] = r1[16];
            g[2] = r2[0]; g[6] = r2[16];
            g[3] = r3[0]; g[7] = r3[16];
        }
        #pragma unroll
        for (int kt = 0; kt < 8; ++kt) {
            bf16x8 a = *(const bf16x8*)(hA + aoff[kt]);
            acc0 = __builtin_amdgcn_mfma_f32_16x16x32_bf16(a, wfh[0][kt], acc0, 0, 0, 0);
            acc1 = __builtin_amdgcn_mfma_f32_16x16x32_bf16(a, wfh[1][kt], acc1, 0, 0, 0);
        }
        #pragma unroll
        for (int r = 0; r < 4; ++r) {
            *(unsigned short*)(hW + woff[r])     = f2bf_fast(fast_tanh(acc0[r]));
            *(unsigned short*)(hW + woff[4 + r]) = f2bf_fast(fast_tanh(acc1[r]));
        }
    };

    #pragma unroll 1
    for (int t4 = 0; t4 < 32; ++t4) {
        step(h0,        h0 + 8192, gA, 4 * t4);
        barrier_lds_only();
        step(h0 + 8192, h0,        gB, 4 * t4 + 1);
        barrier_lds_only();
        step(h0,        h0 + 8192, gC, 4 * t4 + 2);
        barrier_lds_only();
        step(h0 + 8192, h0,        gD, 4 * t4 + 3);
        barrier_lds_only();
    }

    // final h in buf0. Classifier: 4 threads per (row,c), shuffle-reduce.
    if (tid < 320) {
        int q = tid & 3, p = tid >> 2;
        int row = p / 5, c = p - row * 5;
        float acc = 0.f;
        #pragma unroll
        for (int kk = 0; kk < 64; ++kk) {
            int k = q * 64 + kk;
            int off = row * 512 + ((((k >> 3) ^ row)) << 4) + (k & 7) * 2;
            acc += bf2f(*(const unsigned short*)(h0 + off)) * wcls_lds[c * 256 + k];
        }
        acc += __shfl_xor(acc, 1);
        acc += __shfl_xor(acc, 2);
        if (q == 0) out[(size_t)(b0 + row) * 5 + c] = acc + bcls_lds[c];
    }
}

extern "C" void kernel_launch(void* const* d_in, const int* in_sizes, int n_in,
                              void* d_out, int out_size, void* d_ws, size_t ws_size,
                              hipStream_t stream)
{
    const int*   x     = (const int*)d_in[0];
    const float* emb   = (const float*)d_in[1];
    const float* W_ih  = (const float*)d_in[2];
    const float* W_hh  = (const float*)d_in[3];
    const float* b_ih  = (const float*)d_in[4];
    const float* b_hh  = (const float*)d_in[5];
    const float* W_cls = (const float*)d_in[6];
    const float* b_cls = (const float*)d_in[7];
    float*       out   = (float*)d_out;
    (void)d_ws; (void)ws_size;

    void* args[] = { (void*)&x, (void*)&emb, (void*)&W_ih, (void*)&W_hh,
                     (void*)&b_ih, (void*)&b_hh, (void*)&W_cls, (void*)&b_cls,
                     (void*)&out };
    hipLaunchCooperativeKernel((const void*)rnn_fused_kernel,
                               dim3(256), dim3(512), args, 0, stream);
}

// Round 10
// 222.283 us; speedup vs baseline: 1.8403x; 1.3231x over previous
//
#include <hip/hip_runtime.h>

// emb lookup -> RNN tanh(xp_t + h @ W_hh^T) over S=128 -> 5-class head.
// B=4096, S=128, D=256, VOCAB=50000. Floats f32, x int32, out f32.
//
// R16: the R15 cooperative-fused kernel measured 197.8us in-kernel (phase A
// ~60-65us at 8 waves/block vs 95-97us at 4 waves standalone) but the
// cooperative launch added ~96us/iter submission overhead (294us bench).
// Nothing couples the phases except g_P ordering -> extract phase A verbatim
// as a standalone 512-thread kernel and go back to two regular graph-captured
// launches (R4/R6: inter-dispatch gap ~= 0).
//
// Phase 0: 512 thr (8 waves x 2 col-tiles), grid 256, double-buffered tin,
//   ONE lgkm-only barrier per tile, 2-tile register prefetch (static names),
//   direct g_P stores. Exactly the code that measured ~60us inside R15.
// Phase 1: EXACT R6 rnn (130.5us best): depth-4 gather pipeline (gA..gD),
//   lgkm-only barriers, granule-XOR-swizzled h LDS, VGPR=100.

typedef __attribute__((ext_vector_type(8))) short bf16x8;   // 8 bf16 = 4 VGPRs
typedef __attribute__((ext_vector_type(4))) float f32x4;    // MFMA 16x16 accumulator

#define VOCAB 50000
#define LDS_STRIDE 264   // phase-0 staging stride (ushorts)

__device__ __align__(256) unsigned short g_P[VOCAB * 256];  // 25.6 MB projected table

static __device__ __forceinline__ float bf2f(unsigned short u) {
    union { unsigned int i; float f; } v; v.i = ((unsigned int)u) << 16; return v.f;
}
static __device__ __forceinline__ float bfbits2f(unsigned int zext_u16) {
    union { unsigned int i; float f; } v; v.i = zext_u16 << 16; return v.f;
}
static __device__ __forceinline__ unsigned short f2bf_rne(float f) {
    union { float f; unsigned int i; } v; v.f = f;
    unsigned int r = v.i + 0x7FFFu + ((v.i >> 16) & 1u);
    return (unsigned short)(r >> 16);
}
static __device__ __forceinline__ unsigned short f2bf_fast(float f) {   // round-half-up
    union { float f; unsigned int i; } v; v.f = f;
    return (unsigned short)((v.i + 0x8000u) >> 16);
}
static __device__ __forceinline__ bf16x8 cvt8(float4 a, float4 b) {
    bf16x8 r;
    r[0] = (short)f2bf_rne(a.x); r[1] = (short)f2bf_rne(a.y);
    r[2] = (short)f2bf_rne(a.z); r[3] = (short)f2bf_rne(a.w);
    r[4] = (short)f2bf_rne(b.x); r[5] = (short)f2bf_rne(b.y);
    r[6] = (short)f2bf_rne(b.z); r[7] = (short)f2bf_rne(b.w);
    return r;
}
static __device__ __forceinline__ bf16x8 load8_bf(const float* __restrict__ p) {
    return cvt8(((const float4*)p)[0], ((const float4*)p)[1]);
}
// tanh(x) = 1 - 2/(e^{2x}+1); med3 clamp keeps exp finite
static __device__ __forceinline__ float fast_tanh(float x) {
    x = __builtin_amdgcn_fmed3f(x, -8.f, 8.f);
    float e = __expf(2.f * x);
    return __builtin_fmaf(-2.f, __builtin_amdgcn_rcpf(e + 1.f), 1.f);
}
// Workgroup barrier that does NOT drain vmcnt: only LDS ops must be visible.
static __device__ __forceinline__ void barrier_lds_only() {
    asm volatile("s_waitcnt lgkmcnt(0)\n\ts_barrier" ::: "memory");
}

// ---------------- Phase 0: P = bf16(emb @ W_ih^T + (b_ih + b_hh)) ----------------
// 256 blocks x 512 thr (8 waves x 2 col-tiles). Tiles b, b+256, ... (13 max).
// Single lgkm barrier per tile (R4 hazard proof: iter i writes tin[i&1]
// pre-barrier, reads it post-barrier; the buffer overwritten next iter was
// last read pre-barrier(i), which every wave has passed).
__global__ __launch_bounds__(512)
void emb_proj_kernel(const float* __restrict__ emb,
                     const float* __restrict__ W_ih,
                     const float* __restrict__ b_ih,
                     const float* __restrict__ b_hh)
{
    __shared__ __align__(16) unsigned short tin[2][16 * LDS_STRIDE];
    const int tid  = threadIdx.x;
    const int lane = tid & 63;
    const int wid  = tid >> 6;          // 8 waves
    const int b    = blockIdx.x;
    const int n0   = wid * 32;          // wave's 32-col slice
    const int l15  = lane & 15;
    const int quad = lane >> 4;

    bf16x8 wfA[2][8];
    float  biasA[2];
    #pragma unroll
    for (int nt = 0; nt < 2; ++nt) {
        int n = n0 + nt * 16 + l15;
        biasA[nt] = b_ih[n] + b_hh[n];
        #pragma unroll
        for (int kt = 0; kt < 8; ++kt)
            wfA[nt][kt] = load8_bf(W_ih + n * 256 + quad * 8 + kt * 32);
    }

    const int srow = tid >> 5, sseg = tid & 31;   // staging map: 16 rows x 32 segs x 8 floats
    float4 p0a, p0b, p1a, p1b;                     // 2-tile register prefetch (static names)
    {
        const float4* s0 = (const float4*)(emb + ((size_t)b * 16 + srow) * 256 + sseg * 8);
        p0a = s0[0]; p0b = s0[1];
        int t1 = b + 256;
        if (t1 < 3125) {
            const float4* s1 = (const float4*)(emb + ((size_t)t1 * 16 + srow) * 256 + sseg * 8);
            p1a = s1[0]; p1b = s1[1];
        }
    }

    #define PROJ_STEP(I, PA, PB, TBUF)                                                 \
    {                                                                                  \
        int tile = b + (I) * 256;                                                      \
        if (tile < 3125) {                                                             \
            *(bf16x8*)(&TBUF[srow * LDS_STRIDE + sseg * 8]) = cvt8(PA, PB);            \
            int tf = tile + 512;                                                       \
            if (tf < 3125) {                                                           \
                const float4* s = (const float4*)(emb + ((size_t)tf * 16 + srow) * 256 + sseg * 8); \
                PA = s[0]; PB = s[1];                                                  \
            }                                                                          \
            barrier_lds_only();                                                        \
            f32x4 acc0 = (f32x4){0.f, 0.f, 0.f, 0.f};                                  \
            f32x4 acc1 = (f32x4){0.f, 0.f, 0.f, 0.f};                                  \
            _Pragma("unroll")                                                          \
            for (int kt = 0; kt < 8; ++kt) {                                           \
                bf16x8 a = *(bf16x8*)(&TBUF[l15 * LDS_STRIDE + quad * 8 + kt * 32]);   \
                acc0 = __builtin_amdgcn_mfma_f32_16x16x32_bf16(a, wfA[0][kt], acc0, 0, 0, 0); \
                acc1 = __builtin_amdgcn_mfma_f32_16x16x32_bf16(a, wfA[1][kt], acc1, 0, 0, 0); \
            }                                                                          \
            unsigned short* prow = g_P + ((size_t)tile * 16 + quad * 4) * 256 + n0;    \
            _Pragma("unroll")                                                          \
            for (int r = 0; r < 4; ++r) {                                              \
                prow[r * 256 + l15]      = f2bf_rne(acc0[r] + biasA[0]);               \
                prow[r * 256 + 16 + l15] = f2bf_rne(acc1[r] + biasA[1]);               \
            }                                                                          \
        }                                                                              \
    }

    #pragma unroll 1
    for (int i2 = 0; i2 < 7; ++i2) {
        PROJ_STEP(2 * i2,     p0a, p0b, tin[0]);
        PROJ_STEP(2 * i2 + 1, p1a, p1b, tin[1]);
    }
    #undef PROJ_STEP
}

// ---------------- Phase 1: recurrence + classifier (EXACT R6 best, 130.5us) ----------------
// h LDS layout (per 8KB buffer): element (row m, col c) at byte
//   m*512 + (((c>>3) ^ m) << 4) + (c&7)*2      (granule-XOR swizzle, conflict-free writes)
__global__ __launch_bounds__(512, 2)
void rnn_kernel(const int* __restrict__ x,
                const float* __restrict__ W_hh,
                const float* __restrict__ W_cls,
                const float* __restrict__ b_cls,
                float* __restrict__ out)
{
    __shared__ __align__(16) unsigned short h_lds[2][16 * 256];  // 2 x 8 KB
    __shared__ __align__(16) int tok_t[128 * 16];                // [t][row]
    __shared__ __align__(16) float wcls_lds[5 * 256];
    __shared__ float bcls_lds[5];

    const int tid  = threadIdx.x;
    const int lane = tid & 63;
    const int wid  = tid >> 6;          // 8 waves
    const int b0   = blockIdx.x * 16;
    const int n0   = wid * 32;          // wave's 32-col slice
    const int l15  = lane & 15;
    const int quad = lane >> 4;

    // W_hh -> bf16 B-fragments, VGPR-resident
    bf16x8 wf[2][8];
    #pragma unroll
    for (int nt = 0; nt < 2; ++nt) {
        int n = n0 + nt * 16 + l15;
        #pragma unroll
        for (int kt = 0; kt < 8; ++kt)
            wf[nt][kt] = load8_bf(W_hh + n * 256 + quad * 8 + kt * 32);
    }

    // stage tokens transposed: tok_t[t*16 + row]
    {
        int row = tid & 15, tq = tid >> 4;   // tq 0..31
        int4 v = *(const int4*)(x + (size_t)(b0 + row) * 128 + tq * 4);
        tok_t[(tq * 4 + 0) * 16 + row] = v.x;
        tok_t[(tq * 4 + 1) * 16 + row] = v.y;
        tok_t[(tq * 4 + 2) * 16 + row] = v.z;
        tok_t[(tq * 4 + 3) * 16 + row] = v.w;
    }
    if (tid < 320) ((float4*)wcls_lds)[tid] = ((const float4*)W_cls)[tid];
    if (tid < 5)   bcls_lds[tid] = b_cls[tid];
    #pragma unroll
    for (int i = 0; i < 4; ++i) ((unsigned int*)h_lds[0])[tid + i * 512] = 0;

    // precomputed LDS byte offsets (loop-invariant; buf1 = +8192 imm)
    int aoff[8];
    #pragma unroll
    for (int kt = 0; kt < 8; ++kt)
        aoff[kt] = l15 * 512 + (((quad + 4 * kt) ^ l15) << 4);
    int woff[8];   // [nt*4 + r]
    #pragma unroll
    for (int nt = 0; nt < 2; ++nt)
        #pragma unroll
        for (int r = 0; r < 4; ++r) {
            int row = quad * 4 + r;
            int g   = (n0 >> 3) + nt * 2 + (l15 >> 3);
            woff[nt * 4 + r] = row * 512 + ((g ^ row) << 4) + (l15 & 7) * 2;
        }

    const unsigned int colByte = (unsigned int)(n0 + l15) * 2;   // within a g_P row

    // prologue: gather xp(t=0..3) -> gA..gD (4-step-deep pipeline; in-flight
    // gathers survive lgkm-only barriers, counted vmcnt at use)
    unsigned int gA[8], gB[8], gC[8], gD[8];
    #pragma unroll
    for (int r = 0; r < 4; ++r) {
        const int* xr = x + (size_t)(b0 + quad * 4 + r) * 128;
        const unsigned short* p0 = g_P + (size_t)xr[0] * 256 + n0 + l15;
        const unsigned short* p1 = g_P + (size_t)xr[1] * 256 + n0 + l15;
        const unsigned short* p2 = g_P + (size_t)xr[2] * 256 + n0 + l15;
        const unsigned short* p3 = g_P + (size_t)xr[3] * 256 + n0 + l15;
        gA[r] = p0[0]; gA[4 + r] = p0[16];
        gB[r] = p1[0]; gB[4 + r] = p1[16];
        gC[r] = p2[0]; gC[4 + r] = p2[16];
        gD[r] = p3[0]; gD[4 + r] = p3[16];
    }
    barrier_lds_only();

    char* const h0 = (char*)&h_lds[0][0];

    auto step = [&](const char* hA, char* hW, unsigned int* g, int t) {
        // consume g as MFMA C operand (xp pre-added for free)
        f32x4 acc0 = { bfbits2f(g[0]), bfbits2f(g[1]), bfbits2f(g[2]), bfbits2f(g[3]) };
        f32x4 acc1 = { bfbits2f(g[4]), bfbits2f(g[5]), bfbits2f(g[6]), bfbits2f(g[7]) };
        // refill g for t+4 (in flight across 4 barriers)
        if (t + 4 < 128) {
            int4 tk = *(const int4*)&tok_t[(t + 4) * 16 + quad * 4];
            const unsigned short* r0 = (const unsigned short*)((const char*)g_P + ((unsigned int)tk.x * 512 + colByte));
            const unsigned short* r1 = (const unsigned short*)((const char*)g_P + ((unsigned int)tk.y * 512 + colByte));
            const unsigned short* r2 = (const unsigned short*)((const char*)g_P + ((unsigned int)tk.z * 512 + colByte));
            const unsigned short* r3 = (const unsigned short*)((const char*)g_P + ((unsigned int)tk.w * 512 + colByte));
            g[0] = r0[0]; g[4] = r0[16];
            g[1] = r1[0]; g[5] = r1[16];
            g[2] = r2[0]; g[6] = r2[16];
            g[3] = r3[0]; g[7] = r3[16];
        }
        #pragma unroll
        for (int kt = 0; kt < 8; ++kt) {
            bf16x8 a = *(const bf16x8*)(hA + aoff[kt]);
            acc0 = __builtin_amdgcn_mfma_f32_16x16x32_bf16(a, wf[0][kt], acc0, 0, 0, 0);
            acc1 = __builtin_amdgcn_mfma_f32_16x16x32_bf16(a, wf[1][kt], acc1, 0, 0, 0);
        }
        #pragma unroll
        for (int r = 0; r < 4; ++r) {
            *(unsigned short*)(hW + woff[r])     = f2bf_fast(fast_tanh(acc0[r]));
            *(unsigned short*)(hW + woff[4 + r]) = f2bf_fast(fast_tanh(acc1[r]));
        }
    };

    #pragma unroll 1
    for (int t4 = 0; t4 < 32; ++t4) {
        step(h0,        h0 + 8192, gA, 4 * t4);
        barrier_lds_only();
        step(h0 + 8192, h0,        gB, 4 * t4 + 1);
        barrier_lds_only();
        step(h0,        h0 + 8192, gC, 4 * t4 + 2);
        barrier_lds_only();
        step(h0 + 8192, h0,        gD, 4 * t4 + 3);
        barrier_lds_only();
    }

    // final h in buf0 (step 127 wrote buf0). Classifier: 4 threads per (row,c).
    if (tid < 320) {
        int q = tid & 3, p = tid >> 2;
        int row = p / 5, c = p - row * 5;
        float acc = 0.f;
        #pragma unroll
        for (int kk = 0; kk < 64; ++kk) {
            int k = q * 64 + kk;
            int off = row * 512 + ((((k >> 3) ^ row)) << 4) + (k & 7) * 2;
            acc += bf2f(*(const unsigned short*)(h0 + off)) * wcls_lds[c * 256 + k];
        }
        acc += __shfl_xor(acc, 1);
        acc += __shfl_xor(acc, 2);
        if (q == 0) out[(size_t)(b0 + row) * 5 + c] = acc + bcls_lds[c];
    }
}

extern "C" void kernel_launch(void* const* d_in, const int* in_sizes, int n_in,
                              void* d_out, int out_size, void* d_ws, size_t ws_size,
                              hipStream_t stream)
{
    const int*   x     = (const int*)d_in[0];
    const float* emb   = (const float*)d_in[1];
    const float* W_ih  = (const float*)d_in[2];
    const float* W_hh  = (const float*)d_in[3];
    const float* b_ih  = (const float*)d_in[4];
    const float* b_hh  = (const float*)d_in[5];
    const float* W_cls = (const float*)d_in[6];
    const float* b_cls = (const float*)d_in[7];
    float*       out   = (float*)d_out;
    (void)d_ws; (void)ws_size;

    emb_proj_kernel<<<256, 512, 0, stream>>>(emb, W_ih, b_ih, b_hh);
    rnn_kernel<<<256, 512, 0, stream>>>(x, W_hh, W_cls, b_cls, out);
}